// Round 18
// baseline (74.098 us; speedup 1.0000x reference)
//
#include <hip/hip_runtime.h>

#define NB 16     // batches
#define NV 19     // vertices
#define NE 361    // edges per graph
#define NL 256    // seq len
#define ND 64     // d_model
#define NEP 384   // padded edges (24 tiles of 16)
#define ATS 72    // shorts per A_T row (144 B: 16B-aligned, rows advance 4 banks)
#define NPP 4     // (b,l) pairs per persistent block

typedef __attribute__((ext_vector_type(8))) short bf16x8;
typedef __attribute__((ext_vector_type(4))) float f32x4;
typedef __attribute__((ext_vector_type(2))) __bf16 bf16v2;

union bf8u { unsigned u[4]; bf16x8 v; uint4 q; };

__device__ __forceinline__ unsigned pack_bf16(float lo, float hi) {
    bf16v2 v; v.x = (__bf16)lo; v.y = (__bf16)hi;   // -> v_cvt_pk_bf16_f32
    return __builtin_bit_cast(unsigned, v);
}
__device__ __forceinline__ short f2bf(float f) {
    __bf16 h = (__bf16)f;
    return __builtin_bit_cast(short, h);
}
// packed-f32-friendly 4-wide silu: x * rcp(1 + exp2(-x*log2e))
__device__ __forceinline__ f32x4 silu4(f32x4 x) {
    f32x4 t = x * -1.44269504f;
    f32x4 d;
    d.x = __builtin_amdgcn_exp2f(t.x);
    d.y = __builtin_amdgcn_exp2f(t.y);
    d.z = __builtin_amdgcn_exp2f(t.z);
    d.w = __builtin_amdgcn_exp2f(t.w);
    d += 1.f;
    f32x4 r;
    r.x = __builtin_amdgcn_rcpf(d.x);
    r.y = __builtin_amdgcn_rcpf(d.y);
    r.z = __builtin_amdgcn_rcpf(d.z);
    r.w = __builtin_amdgcn_rcpf(d.w);
    return x * r;
}
__device__ __forceinline__ float sigm(float x) {
    return __builtin_amdgcn_rcpf(1.f + __builtin_amdgcn_exp2f(x * -1.44269504f));
}

// PERSISTENT block: 4 consecutive (b,l) pairs, 256 threads = 4 waves, grid 1024.
// Per-pair: phase2 (MFMA A build, transposed) -> barrier -> hoist afr/mr to regs
// -> barrier -> phase3 (register-only tiles) WITH next pair's meta staged under it.
// Constants/w1f/A_T-zero amortized over 4 pairs. (256,4): 128-reg cap (tighter spills,
// r5/r9/r12/r15). Spill tripwire: WRITE_SIZE must stay 5.776 MB.
__global__ __launch_bounds__(256, 4) void edge_learner_kernel(
    const float* __restrict__ hs,      // (B*V, L, D)
    const float* __restrict__ ew_in,   // (B*E, L)
    const float* __restrict__ W1,      // (129, 64)
    const float* __restrict__ b1,      // (64,)
    const float* __restrict__ W2,      // (64, 32)
    const float* __restrict__ b2,      // (32,)
    const float* __restrict__ W3,      // (32, 1)
    const float* __restrict__ b3,      // (1,)
    const float* __restrict__ skip_p,  // (1,)
    const int*   __restrict__ eidx,    // (2, B*E, L)
    float* __restrict__ out)           // (B*E, L)
{
    __shared__ __align__(16) short A_T[64 * ATS];   // transposed node projections
    __shared__ __align__(8)  uint2 meta_s[NEP];     // {src | tgt<<16, ew_bits}

    const int tid  = threadIdx.x;
    const int lane = tid & 63;
    const int wave = tid >> 6;
    const int lq   = lane >> 4;    // quarter (k-group)
    const int lm   = lane & 15;    // row/col within fragment
    // XCD-contiguous swizzle over 1024 blocks (1024 % 8 == 0, bijective)
    const int bid0 = blockIdx.x;
    const int bid  = (bid0 & 7) * 128 + (bid0 >> 3);
    const int plb  = bid * NPP;    // first pair; 4 | 256 so b constant per block
    const int b    = plb >> 8;
    const int l0   = plb & 255;

    // ---------- zero A_T ONCE (pad cols stay 0 across all pairs) ----------
    for (int i = tid; i < 64 * ATS / 8; i += 256) {
        uint4 z; z.x = 0; z.y = 0; z.z = 0; z.w = 0;
        *(uint4*)&A_T[i * 8] = z;
    }

    // ---------- stage pair-0 edge metadata ----------
    for (int e = tid; e < NEP; e += 256) {
        uint2 m;
        if (e < NE) {
            size_t row = (size_t)(b * NE + e) * NL + l0;
            unsigned s = (unsigned)(eidx[row] % NV);
            unsigned t = (unsigned)(eidx[(size_t)NB * NE * NL + row] % NV);
            m.x = s | (t << 16);
            m.y = __builtin_bit_cast(unsigned, ew_in[row]);
        } else {
            m.x = 0; m.y = 0;
        }
        meta_s[e] = m;
    }

    // ---------- persistent per-lane constants (paid once per 4 pairs) ----------
    bf8u w2f[2][2];                // MFMA A operand = W2^T rows j = nt*16+lm
    #pragma unroll
    for (int nt = 0; nt < 2; ++nt)
        #pragma unroll
        for (int ks = 0; ks < 2; ++ks) {
            const float* w2p = &W2[(ks * 32 + lq * 8) * 32 + nt * 16 + lm];
            #pragma unroll
            for (int p = 0; p < 4; ++p)
                w2f[nt][ks].u[p] = pack_bf16(w2p[(2 * p) * 32], w2p[(2 * p + 1) * 32]);
        }
    const f32x4 b2v0 = *(const f32x4*)&b2[lq * 4];
    const f32x4 b2v1 = *(const f32x4*)&b2[16 + lq * 4];
    const f32x4 w3v0 = *(const f32x4*)&W3[lq * 4];
    const f32x4 w3v1 = *(const f32x4*)&W3[16 + lq * 4];
    const float b3v  = b3[0];
    const float skip = skip_p[0];

    // phase-2 weights + bias, pair-independent -> persistent registers
    const int half = wave >> 1;
    const int oc0  = (wave & 1) * 32;
    const float hb0 = 0.5f * b1[(wave * 32 + lm) & 63];
    const float hb1 = 0.5f * b1[(wave * 32 + 16 + lm) & 63];
    bf8u w1f[2][2];   // [nt][ks]
    #pragma unroll
    for (int nt = 0; nt < 2; ++nt)
        #pragma unroll
        for (int ks = 0; ks < 2; ++ks) {
            const float* wp = &W1[(half * 64 + ks * 32 + lq * 8) * 64
                                  + oc0 + nt * 16 + lm];
            #pragma unroll
            for (int p = 0; p < 4; ++p)
                w1f[nt][ks].u[p] = pack_bf16(wp[(2 * p) * 64], wp[(2 * p + 1) * 64]);
        }

    __syncthreads();   // zero-init visible before any A_T data writes

    // ---------- w1l row ONCE: A_T[c][31] = W1[128][c] ----------
    if (tid < 64) A_T[tid * ATS + 31] = f2bf(W1[128 * 64 + tid]);

    // ================= persistent loop over 4 pairs =================
    #pragma unroll 1
    for (int it = 0; it < NPP; ++it) {
        const int l = l0 + it;

        // ---------- phase 2: A via MFMA, TRANSPOSED writes ----------
        {
            f32x4 acc00 = {0,0,0,0}, acc01 = {0,0,0,0},
                  acc10 = {0,0,0,0}, acc11 = {0,0,0,0};
            #pragma unroll
            for (int Mt = 0; Mt < 2; ++Mt) {
                int v  = Mt * 16 + lm;
                int vc = v < NV ? v : NV - 1;        // clamp pad rows
                const float* hp = hs + ((size_t)(b * NV + vc) * NL + l) * ND;
                bf8u af[2];
                #pragma unroll
                for (int ks = 0; ks < 2; ++ks) {
                    float4 x0 = *(const float4*)&hp[ks * 32 + lq * 8];
                    float4 x1 = *(const float4*)&hp[ks * 32 + lq * 8 + 4];
                    af[ks].u[0] = pack_bf16(x0.x, x0.y);
                    af[ks].u[1] = pack_bf16(x0.z, x0.w);
                    af[ks].u[2] = pack_bf16(x1.x, x1.y);
                    af[ks].u[3] = pack_bf16(x1.z, x1.w);
                }
                if (Mt == 0) {
                    acc00 = __builtin_amdgcn_mfma_f32_16x16x32_bf16(af[0].v, w1f[0][0].v, acc00, 0, 0, 0);
                    acc00 = __builtin_amdgcn_mfma_f32_16x16x32_bf16(af[1].v, w1f[0][1].v, acc00, 0, 0, 0);
                    acc01 = __builtin_amdgcn_mfma_f32_16x16x32_bf16(af[0].v, w1f[1][0].v, acc01, 0, 0, 0);
                    acc01 = __builtin_amdgcn_mfma_f32_16x16x32_bf16(af[1].v, w1f[1][1].v, acc01, 0, 0, 0);
                } else {
                    acc10 = __builtin_amdgcn_mfma_f32_16x16x32_bf16(af[0].v, w1f[0][0].v, acc10, 0, 0, 0);
                    acc10 = __builtin_amdgcn_mfma_f32_16x16x32_bf16(af[1].v, w1f[0][1].v, acc10, 0, 0, 0);
                    acc11 = __builtin_amdgcn_mfma_f32_16x16x32_bf16(af[0].v, w1f[1][0].v, acc11, 0, 0, 0);
                    acc11 = __builtin_amdgcn_mfma_f32_16x16x32_bf16(af[1].v, w1f[1][1].v, acc11, 0, 0, 0);
                }
            }
            // transposed write: A col c = wave*32+{lm,16+lm} -> A_T row (c&63),
            // col = v (waves 0,1 = src part) or 32+v (waves 2,3 = tgt part)
            const int tr0 = (wave & 1) * 32 + lm;
            const int tr1 = (wave & 1) * 32 + 16 + lm;
            const int cof = (wave >> 1) * 32;
            #pragma unroll
            for (int r = 0; r < 4; ++r) {
                int v0 = lq * 4 + r;
                A_T[tr0 * ATS + cof + v0] = f2bf(acc00[r] + hb0);
                A_T[tr1 * ATS + cof + v0] = f2bf(acc01[r] + hb1);
                int v1 = 16 + lq * 4 + r;
                if (v1 < NV) {
                    A_T[tr0 * ATS + cof + v1] = f2bf(acc10[r] + hb0);
                    A_T[tr1 * ATS + cof + v1] = f2bf(acc11[r] + hb1);
                }
            }
        }
        __syncthreads();   // BARRIER A: A_T(cur) + meta_s(cur) ready

        // ---------- hoist fragments + meta to registers ----------
        bf8u afr[4][2];
        #pragma unroll
        for (int mt = 0; mt < 4; ++mt) {
            const int c = (mt >> 1) * 32 + (mt & 1) * 4 + ((lm >> 2) << 3) + (lm & 3);
            #pragma unroll
            for (int kc = 0; kc < 2; ++kc)
                afr[mt][kc].q = *(const uint4*)&A_T[c * ATS + kc * 32 + lq * 8];
        }
        uint2 mr[6];
        #pragma unroll
        for (int i = 0; i < 6; ++i)
            mr[i] = meta_s[(wave + 4 * i) * 16 + lm];
        __syncthreads();   // BARRIER B: all regs hoisted; LDS free for restage

        // ---------- stage NEXT pair's meta (latency hides under phase 3) ----------
        if (it < NPP - 1) {
            const int ln = l + 1;
            for (int e = tid; e < NEP; e += 256) {
                uint2 m;
                if (e < NE) {
                    size_t row = (size_t)(b * NE + e) * NL + ln;
                    unsigned s = (unsigned)(eidx[row] % NV);
                    unsigned t = (unsigned)(eidx[(size_t)NB * NE * NL + row] % NV);
                    m.x = s | (t << 16);
                    m.y = __builtin_bit_cast(unsigned, ew_in[row]);
                } else {
                    m.x = 0; m.y = 0;
                }
                meta_s[e] = m;
            }
        }

        // ---------- phase 3: 6 tiles/wave, register-only ----------
        #pragma unroll
        for (int i = 0; i < 6; ++i) {
            const int t = wave + 4 * i;
            const int src = (int)(mr[i].x & 0xffffu);
            const int tgt = (int)(mr[i].x >> 16);
            const float ew = __builtin_bit_cast(float, mr[i].y);

            // build S fragments in registers: col = edge lm, k-slots lq*8 + j
            bf8u s0, s1;
            {
                const int base = lq * 8;
                int w  = src - base;
                int ix = w >> 1;
                unsigned pat = (w & 1) ? 0x3F800000u : 0x3F80u;   // bf16 1.0 hi/lo
                s0.u[0] = (ix == 0) ? pat : 0u;
                s0.u[1] = (ix == 1) ? pat : 0u;
                s0.u[2] = (ix == 2) ? pat : 0u;
                s0.u[3] = (ix == 3) ? pat : 0u;
                unsigned ewm = (lq == 3) ? (((unsigned)(unsigned short)f2bf(ew)) << 16) : 0u;
                s0.u[3] |= ewm;
                int w2_ = tgt - base;
                int ix2 = w2_ >> 1;
                unsigned pat2 = (w2_ & 1) ? 0x3F800000u : 0x3F80u;
                s1.u[0] = (ix2 == 0) ? pat2 : 0u;
                s1.u[1] = (ix2 == 1) ? pat2 : 0u;
                s1.u[2] = (ix2 == 2) ? pat2 : 0u;
                s1.u[3] = (ix2 == 3) ? pat2 : 0u;
            }

            // z = A_T^T @ S^T (8 MFMAs): z lands in layer-2 B-fragment layout
            f32x4 z0 = {0,0,0,0}, z1 = {0,0,0,0}, z2 = {0,0,0,0}, z3 = {0,0,0,0};
            z0 = __builtin_amdgcn_mfma_f32_16x16x32_bf16(afr[0][0].v, s0.v, z0, 0, 0, 0);
            z0 = __builtin_amdgcn_mfma_f32_16x16x32_bf16(afr[0][1].v, s1.v, z0, 0, 0, 0);
            z1 = __builtin_amdgcn_mfma_f32_16x16x32_bf16(afr[1][0].v, s0.v, z1, 0, 0, 0);
            z1 = __builtin_amdgcn_mfma_f32_16x16x32_bf16(afr[1][1].v, s1.v, z1, 0, 0, 0);
            z2 = __builtin_amdgcn_mfma_f32_16x16x32_bf16(afr[2][0].v, s0.v, z2, 0, 0, 0);
            z2 = __builtin_amdgcn_mfma_f32_16x16x32_bf16(afr[2][1].v, s1.v, z2, 0, 0, 0);
            z3 = __builtin_amdgcn_mfma_f32_16x16x32_bf16(afr[3][0].v, s0.v, z3, 0, 0, 0);
            z3 = __builtin_amdgcn_mfma_f32_16x16x32_bf16(afr[3][1].v, s1.v, z3, 0, 0, 0);

            // silu + pack straight into layer-2 B fragments
            f32x4 y0 = silu4(z0), y1 = silu4(z1), y2 = silu4(z2), y3 = silu4(z3);
            bf8u a1[2];
            a1[0].u[0] = pack_bf16(y0.x, y0.y);
            a1[0].u[1] = pack_bf16(y0.z, y0.w);
            a1[0].u[2] = pack_bf16(y1.x, y1.y);
            a1[0].u[3] = pack_bf16(y1.z, y1.w);
            a1[1].u[0] = pack_bf16(y2.x, y2.y);
            a1[1].u[1] = pack_bf16(y2.z, y2.w);
            a1[1].u[2] = pack_bf16(y3.x, y3.y);
            a1[1].u[3] = pack_bf16(y3.z, y3.w);

            // layer 2: W2^T @ h1^T -> C[row=j, col=edge]  (4 MFMAs)
            f32x4 c0 = {0,0,0,0}, c1 = {0,0,0,0};
            c0 = __builtin_amdgcn_mfma_f32_16x16x32_bf16(w2f[0][0].v, a1[0].v, c0, 0, 0, 0);
            c0 = __builtin_amdgcn_mfma_f32_16x16x32_bf16(w2f[0][1].v, a1[1].v, c0, 0, 0, 0);
            c1 = __builtin_amdgcn_mfma_f32_16x16x32_bf16(w2f[1][0].v, a1[0].v, c1, 0, 0, 0);
            c1 = __builtin_amdgcn_mfma_f32_16x16x32_bf16(w2f[1][1].v, a1[1].v, c1, 0, 0, 0);

            // epilogue: silu over this lane's 8 j-rows, W3 dot, 2-shuffle reduce
            f32x4 h0 = silu4(c0 + b2v0);
            f32x4 h1 = silu4(c1 + b2v1);
            f32x4 pv = h0 * w3v0 + h1 * w3v1;
            float p  = (pv.x + pv.y) + (pv.z + pv.w);
            p += __shfl_xor(p, 16);
            p += __shfl_xor(p, 32);

            if (lane < 16) {
                int er = t * 16 + lane;
                if (er < NE) {
                    float wgt = sigm(p + b3v);
                    out[(size_t)(b * NE + er) * NL + l] = skip * ew + (1.f - skip) * wgt;
                }
            }
        }
        // no end-of-pair barrier needed: phase 3 reads only registers; next
        // phase 2 writes A_T (not read until after BARRIER A), meta_s already
        // restaged behind BARRIER B.
    }
}

extern "C" void kernel_launch(void* const* d_in, const int* in_sizes, int n_in,
                              void* d_out, int out_size, void* d_ws, size_t ws_size,
                              hipStream_t stream) {
    const float* hs   = (const float*)d_in[0];
    const float* ew   = (const float*)d_in[1];
    const float* W1   = (const float*)d_in[2];
    const float* b1   = (const float*)d_in[3];
    const float* W2   = (const float*)d_in[4];
    const float* b2   = (const float*)d_in[5];
    const float* W3   = (const float*)d_in[6];
    const float* b3   = (const float*)d_in[7];
    const float* skip = (const float*)d_in[8];
    const int*   eidx = (const int*)d_in[9];
    float* outp = (float*)d_out;

    dim3 grid(NB * NL / NPP);   // 1024 persistent blocks, 4 pairs each
    dim3 block(256);
    hipLaunchKernelGGL(edge_learner_kernel, grid, block, 0, stream,
                       hs, ew, W1, b1, W2, b2, W3, b3, skip, eidx, outp);
}

// Round 19
// 57.312 us; speedup vs baseline: 1.2929x; 1.2929x over previous
//
#include <hip/hip_runtime.h>

#define NB 16     // batches
#define NV 19     // vertices
#define NE 361    // edges per graph
#define NL 256    // seq len
#define ND 64     // d_model
#define NTP 24    // padded tile count (exactly 6 per wave, no guards)
#define NEP (NTP * 16)  // 384 padded edges
#define ASTRIDE 136     // bf16 shorts per A row (272 B, 16B-aligned)

typedef __attribute__((ext_vector_type(8))) short bf16x8;
typedef __attribute__((ext_vector_type(4))) float f32x4;
typedef __attribute__((ext_vector_type(2))) __bf16 bf16v2;

union bf8u { unsigned u[4]; bf16x8 v; uint4 q; };

__device__ __forceinline__ unsigned pack_bf16(float lo, float hi) {
    bf16v2 v; v.x = (__bf16)lo; v.y = (__bf16)hi;   // -> v_cvt_pk_bf16_f32
    return __builtin_bit_cast(unsigned, v);
}
__device__ __forceinline__ short f2bf(float f) {
    __bf16 h = (__bf16)f;
    return __builtin_bit_cast(short, h);
}
__device__ __forceinline__ float bflo(unsigned u) {
    return __builtin_bit_cast(float, u << 16);
}
__device__ __forceinline__ float bfhi(unsigned u) {
    return __builtin_bit_cast(float, u & 0xffff0000u);
}
// packed-f32-friendly 4-wide silu: x * rcp(1 + exp2(-x*log2e))
__device__ __forceinline__ f32x4 silu4(f32x4 x) {
    f32x4 t = x * -1.44269504f;
    f32x4 d;
    d.x = __builtin_amdgcn_exp2f(t.x);
    d.y = __builtin_amdgcn_exp2f(t.y);
    d.z = __builtin_amdgcn_exp2f(t.z);
    d.w = __builtin_amdgcn_exp2f(t.w);
    d += 1.f;
    f32x4 r;
    r.x = __builtin_amdgcn_rcpf(d.x);
    r.y = __builtin_amdgcn_rcpf(d.y);
    r.z = __builtin_amdgcn_rcpf(d.z);
    r.w = __builtin_amdgcn_rcpf(d.w);
    return x * r;
}
__device__ __forceinline__ float sigm(float x) {
    return __builtin_amdgcn_rcpf(1.f + __builtin_amdgcn_exp2f(x * -1.44269504f));
}

// One block per (b, l). 256 threads = 4 waves.
// launch_bounds(256,5): ~96-102 unified-VGPR cap, 5 blocks/CU. Kernel demand
// ~72-88 unified (44 arch VGPR measured) — no spill at this cap (r13 verified).
// Register-pressure history: (256,6)=85 cap barely spilled with pipeline (r12),
// (256,8)=64 spilled badly (r9). Spill tripwire: WRITE_SIZE must stay 5.776 MB.
//
// SESSION PLATEAU NOTE (r7..r18): five structures converge at 57.2-57.8 us.
// busy = ~36 us/SIMD of VALU+trans issue (96 silu + 1 sigm per edge is
// algorithmically fixed); wall = busy / ~0.63 issue-efficiency; efficiency is
// pinned by the 128-unified-reg cliff (4 blocks/CU). Occupancy raises, setprio,
// pipelining, meta-hoist, MFMA-gather layer-1, kernel split, persistence all
// measured neutral-or-worse. This (r13) is the champion configuration.
__global__ __launch_bounds__(256, 5) void edge_learner_kernel(
    const float* __restrict__ hs,      // (B*V, L, D)
    const float* __restrict__ ew_in,   // (B*E, L)
    const float* __restrict__ W1,      // (129, 64)
    const float* __restrict__ b1,      // (64,)
    const float* __restrict__ W2,      // (64, 32)
    const float* __restrict__ b2,      // (32,)
    const float* __restrict__ W3,      // (32, 1)
    const float* __restrict__ b3,      // (1,)
    const float* __restrict__ skip_p,  // (1,)
    const int*   __restrict__ eidx,    // (2, B*E, L)
    float* __restrict__ out)           // (B*E, L)
{
    __shared__ __align__(16) short A_s[NV * ASTRIDE];  // node projs + 0.5*b1 baked, bf16
    __shared__ __align__(8)  uint2 meta_s[NEP];        // {src|tgt<<16, ew_bits}

    const int tid  = threadIdx.x;
    const int lane = tid & 63;
    const int wave = tid >> 6;
    const int lq   = lane >> 4;    // quarter (k-group)
    const int lm   = lane & 15;    // row/col within fragment
    // XCD-contiguous swizzle (4096 % 8 == 0, bijective)
    const int bid0 = blockIdx.x;
    const int bid  = (bid0 & 7) * 512 + (bid0 >> 3);
    const int b    = bid >> 8;
    const int l    = bid & 255;

    // ---------- stage edge metadata (8 B/edge) ----------
    for (int e = tid; e < NEP; e += 256) {
        uint2 m;
        if (e < NE) {
            size_t row = (size_t)(b * NE + e) * NL + l;
            unsigned so = (unsigned)((eidx[row] % NV) * ASTRIDE);
            unsigned to = (unsigned)((eidx[(size_t)NB * NE * NL + row] % NV) * ASTRIDE + 64);
            m.x = so | (to << 16);
            m.y = __builtin_bit_cast(unsigned, ew_in[row]);
        } else {
            m.x = 64u << 16; m.y = 0u;
        }
        meta_s[e] = m;
    }

    // ---------- per-lane constants (registers) ----------
    // layer-1 edge-weight row, channels ch(ks,i) = ks*32 + lq*8 + i  (b1 baked into A)
    f32x4 w1lv[2][2];
    #pragma unroll
    for (int ks = 0; ks < 2; ++ks) {
        w1lv[ks][0] = *(const f32x4*)&W1[128 * 64 + ks * 32 + lq * 8];
        w1lv[ks][1] = *(const f32x4*)&W1[128 * 64 + ks * 32 + lq * 8 + 4];
    }
    // W2 fragments (MFMA *A* operand = W2^T rows j = nt*16+lm)
    bf8u w2f[2][2];
    #pragma unroll
    for (int nt = 0; nt < 2; ++nt)
        #pragma unroll
        for (int ks = 0; ks < 2; ++ks) {
            const float* w2p = &W2[(ks * 32 + lq * 8) * 32 + nt * 16 + lm];
            #pragma unroll
            for (int p = 0; p < 4; ++p)
                w2f[nt][ks].u[p] = pack_bf16(w2p[(2 * p) * 32], w2p[(2 * p + 1) * 32]);
        }
    // epilogue constants: this lane's C rows j = {lq*4.., 16+lq*4..}
    const f32x4 b2v0 = *(const f32x4*)&b2[lq * 4];
    const f32x4 b2v1 = *(const f32x4*)&b2[16 + lq * 4];
    const f32x4 w3v0 = *(const f32x4*)&W3[lq * 4];
    const f32x4 w3v1 = *(const f32x4*)&W3[16 + lq * 4];
    const float b3v  = b3[0];
    const float skip = skip_p[0];

    // ---------- phase 2: A[v][c] via MFMA; wave w owns cols [32w, 32w+32) ----------
    {
        const int half = wave >> 1;
        const int oc0  = (wave & 1) * 32;
        // half of b1 baked into each A half (src cols get 0.5*b1, tgt cols 0.5*b1)
        const float hb0 = 0.5f * b1[(wave * 32 + lm) & 63];
        const float hb1 = 0.5f * b1[(wave * 32 + 16 + lm) & 63];
        bf8u w1f[2][2];   // [nt][ks]
        #pragma unroll
        for (int nt = 0; nt < 2; ++nt)
            #pragma unroll
            for (int ks = 0; ks < 2; ++ks) {
                const float* wp = &W1[(half * 64 + ks * 32 + lq * 8) * 64
                                      + oc0 + nt * 16 + lm];
                #pragma unroll
                for (int p = 0; p < 4; ++p)
                    w1f[nt][ks].u[p] = pack_bf16(wp[(2 * p) * 64], wp[(2 * p + 1) * 64]);
            }

        f32x4 acc00 = {0,0,0,0}, acc01 = {0,0,0,0}, acc10 = {0,0,0,0}, acc11 = {0,0,0,0};
        #pragma unroll
        for (int Mt = 0; Mt < 2; ++Mt) {
            int v  = Mt * 16 + lm;
            int vc = v < NV ? v : NV - 1;            // clamp pad rows
            const float* hp = hs + ((size_t)(b * NV + vc) * NL + l) * ND;
            bf8u af[2];
            #pragma unroll
            for (int ks = 0; ks < 2; ++ks) {
                float4 x0 = *(const float4*)&hp[ks * 32 + lq * 8];
                float4 x1 = *(const float4*)&hp[ks * 32 + lq * 8 + 4];
                af[ks].u[0] = pack_bf16(x0.x, x0.y);
                af[ks].u[1] = pack_bf16(x0.z, x0.w);
                af[ks].u[2] = pack_bf16(x1.x, x1.y);
                af[ks].u[3] = pack_bf16(x1.z, x1.w);
            }
            if (Mt == 0) {
                acc00 = __builtin_amdgcn_mfma_f32_16x16x32_bf16(af[0].v, w1f[0][0].v, acc00, 0, 0, 0);
                acc00 = __builtin_amdgcn_mfma_f32_16x16x32_bf16(af[1].v, w1f[0][1].v, acc00, 0, 0, 0);
                acc01 = __builtin_amdgcn_mfma_f32_16x16x32_bf16(af[0].v, w1f[1][0].v, acc01, 0, 0, 0);
                acc01 = __builtin_amdgcn_mfma_f32_16x16x32_bf16(af[1].v, w1f[1][1].v, acc01, 0, 0, 0);
            } else {
                acc10 = __builtin_amdgcn_mfma_f32_16x16x32_bf16(af[0].v, w1f[0][0].v, acc10, 0, 0, 0);
                acc10 = __builtin_amdgcn_mfma_f32_16x16x32_bf16(af[1].v, w1f[0][1].v, acc10, 0, 0, 0);
                acc11 = __builtin_amdgcn_mfma_f32_16x16x32_bf16(af[0].v, w1f[1][0].v, acc11, 0, 0, 0);
                acc11 = __builtin_amdgcn_mfma_f32_16x16x32_bf16(af[1].v, w1f[1][1].v, acc11, 0, 0, 0);
            }
        }
        // write A (bf16, +0.5*b1): row v, col c = wave*32 + {lm, 16+lm}
        #pragma unroll
        for (int r = 0; r < 4; ++r) {
            int v0 = lq * 4 + r;
            A_s[v0 * ASTRIDE + wave * 32 + lm]      = f2bf(acc00[r] + hb0);
            A_s[v0 * ASTRIDE + wave * 32 + 16 + lm] = f2bf(acc01[r] + hb1);
            int v1 = 16 + lq * 4 + r;
            if (v1 < NV) {
                A_s[v1 * ASTRIDE + wave * 32 + lm]      = f2bf(acc10[r] + hb0);
                A_s[v1 * ASTRIDE + wave * 32 + 16 + lm] = f2bf(acc11[r] + hb1);
            }
        }
    }
    __syncthreads();

    // ---------- phase 3: 6 tiles/wave ----------
    #pragma unroll
    for (int i = 0; i < 6; ++i) {
        const int t = wave + 4 * i;
        const uint2 m = meta_s[t * 16 + lm];
        const int so = (int)(m.x & 0xffffu);
        const int to = (int)(m.x >> 16);
        const float ew = __builtin_bit_cast(float, m.y);

        // layer 1: bf16 gathers, pairwise unpack, packed math, silu, repack
        bf8u a1[2];
        #pragma unroll
        for (int ks = 0; ks < 2; ++ks) {
            const uint4 as = *(const uint4*)&A_s[so + ks * 32 + lq * 8];
            const uint4 at = *(const uint4*)&A_s[to + ks * 32 + lq * 8];
            f32x4 x0, x1;
            x0.x = bflo(as.x) + bflo(at.x);
            x0.y = bfhi(as.x) + bfhi(at.x);
            x0.z = bflo(as.y) + bflo(at.y);
            x0.w = bfhi(as.y) + bfhi(at.y);
            x1.x = bflo(as.z) + bflo(at.z);
            x1.y = bfhi(as.z) + bfhi(at.z);
            x1.z = bflo(as.w) + bflo(at.w);
            x1.w = bfhi(as.w) + bfhi(at.w);
            x0 += ew * w1lv[ks][0];
            x1 += ew * w1lv[ks][1];
            f32x4 y0 = silu4(x0);
            f32x4 y1 = silu4(x1);
            a1[ks].u[0] = pack_bf16(y0.x, y0.y);
            a1[ks].u[1] = pack_bf16(y0.z, y0.w);
            a1[ks].u[2] = pack_bf16(y1.x, y1.y);
            a1[ks].u[3] = pack_bf16(y1.z, y1.w);
        }

        // layer 2: W2^T @ h1^T -> C[row=j, col=edge]  (4 MFMAs)
        f32x4 c0 = {0,0,0,0}, c1 = {0,0,0,0};
        c0 = __builtin_amdgcn_mfma_f32_16x16x32_bf16(w2f[0][0].v, a1[0].v, c0, 0, 0, 0);
        c0 = __builtin_amdgcn_mfma_f32_16x16x32_bf16(w2f[0][1].v, a1[1].v, c0, 0, 0, 0);
        c1 = __builtin_amdgcn_mfma_f32_16x16x32_bf16(w2f[1][0].v, a1[0].v, c1, 0, 0, 0);
        c1 = __builtin_amdgcn_mfma_f32_16x16x32_bf16(w2f[1][1].v, a1[1].v, c1, 0, 0, 0);

        // epilogue: silu over this lane's 8 j-rows (col = edge lm),
        // local dot with W3, 2-shuffle reduce over lq groups
        f32x4 h0 = silu4(c0 + b2v0);
        f32x4 h1 = silu4(c1 + b2v1);
        f32x4 pv = h0 * w3v0 + h1 * w3v1;
        float p  = (pv.x + pv.y) + (pv.z + pv.w);
        p += __shfl_xor(p, 16);
        p += __shfl_xor(p, 32);

        if (lane < 16) {
            int er = t * 16 + lane;
            if (er < NE) {
                float wgt = sigm(p + b3v);
                out[(size_t)(b * NE + er) * NL + l] = skip * ew + (1.f - skip) * wgt;
            }
        }
    }
}

extern "C" void kernel_launch(void* const* d_in, const int* in_sizes, int n_in,
                              void* d_out, int out_size, void* d_ws, size_t ws_size,
                              hipStream_t stream) {
    const float* hs   = (const float*)d_in[0];
    const float* ew   = (const float*)d_in[1];
    const float* W1   = (const float*)d_in[2];
    const float* b1   = (const float*)d_in[3];
    const float* W2   = (const float*)d_in[4];
    const float* b2   = (const float*)d_in[5];
    const float* W3   = (const float*)d_in[6];
    const float* b3   = (const float*)d_in[7];
    const float* skip = (const float*)d_in[8];
    const int*   eidx = (const int*)d_in[9];
    float* outp = (float*)d_out;

    dim3 grid(NB * NL);   // 4096 blocks, one per (b, l)
    dim3 block(256);
    hipLaunchKernelGGL(edge_learner_kernel, grid, block, 0, stream,
                       hs, ew, W1, b1, W2, b2, W3, b3, skip, eidx, outp);
}